// Round 2
// baseline (5263.056 us; speedup 1.0000x reference)
//
#include <hip/hip_runtime.h>
#include <math.h>

constexpr int Bv = 8, Tv = 2048, Cv = 768, Hv = 3072;
constexpr int BT = Bv * Tv;            // 16384 tokens
constexpr int BC = Bv * Cv;            // 6144 channels
constexpr int Lc = 128;                // WKV chunk length
constexpr int NCHK = Tv / Lc;          // 16 checkpoints

// ---------------- LayerNorm: one block per row of 768 ----------------
__global__ __launch_bounds__(256) void ln_kernel(const float* __restrict__ x,
    const float* __restrict__ w, const float* __restrict__ b, float* __restrict__ out)
{
    __shared__ float sh[8];
    int row = blockIdx.x;
    const float* xr = x + (size_t)row * Cv;
    float vals[3];
    float s = 0.f, s2 = 0.f;
#pragma unroll
    for (int i = 0; i < 3; i++) {
        float t = xr[threadIdx.x + 256 * i];
        vals[i] = t; s += t; s2 += t * t;
    }
#pragma unroll
    for (int off = 32; off > 0; off >>= 1) {
        s  += __shfl_down(s, off);
        s2 += __shfl_down(s2, off);
    }
    int wid = threadIdx.x >> 6;
    if ((threadIdx.x & 63) == 0) { sh[wid] = s; sh[4 + wid] = s2; }
    __syncthreads();
    if (threadIdx.x == 0) {
        sh[0] = sh[0] + sh[1] + sh[2] + sh[3];
        sh[4] = sh[4] + sh[5] + sh[6] + sh[7];
    }
    __syncthreads();
    float mean = sh[0] * (1.f / Cv);
    float var  = sh[4] * (1.f / Cv) - mean * mean;
    float rstd = rsqrtf(var + 1e-5f);
    float* orow = out + (size_t)row * Cv;
#pragma unroll
    for (int i = 0; i < 3; i++) {
        int j = threadIdx.x + 256 * i;
        orow[j] = (vals[i] - mean) * rstd * w[j] + b[j];
    }
}

// ---------------- fp32 tiled GEMM: out = A @ W^T (+ epilogue) ----------------
// A: M x K row-major.  W: N x K row-major.  M,N % 64 == 0, K % 16 == 0.
// EPI: 0 none, 1 sigmoid, 2 relu^2, 3 out = e0 + e1 * acc
template<int EPI>
__global__ __launch_bounds__(256) void gemm_nt(const float* __restrict__ A,
    const float* __restrict__ W, float* __restrict__ out,
    int M, int N, int K, const float* __restrict__ e0, const float* __restrict__ e1)
{
    __shared__ float As[16][72];
    __shared__ float Bs[16][72];
    const int tid = threadIdx.x;
    const int bm = blockIdx.x * 64;
    const int bn = blockIdx.y * 64;
    const int lr = tid >> 2;
    const int lk = (tid & 3) * 4;
    const int ty = tid >> 4;
    const int tx = tid & 15;
    float acc[4][4] = {};
    const float* Ap = A + (size_t)(bm + lr) * K + lk;
    const float* Wp = W + (size_t)(bn + lr) * K + lk;
    for (int k0 = 0; k0 < K; k0 += 16) {
        float4 av = *(const float4*)(Ap + k0);
        float4 bv = *(const float4*)(Wp + k0);
        __syncthreads();
        As[lk + 0][lr] = av.x; As[lk + 1][lr] = av.y; As[lk + 2][lr] = av.z; As[lk + 3][lr] = av.w;
        Bs[lk + 0][lr] = bv.x; Bs[lk + 1][lr] = bv.y; Bs[lk + 2][lr] = bv.z; Bs[lk + 3][lr] = bv.w;
        __syncthreads();
#pragma unroll
        for (int kk = 0; kk < 16; kk++) {
            float4 a4 = *(const float4*)&As[kk][ty * 4];
            float4 b4 = *(const float4*)&Bs[kk][tx * 4];
            float aa[4] = {a4.x, a4.y, a4.z, a4.w};
            float bb[4] = {b4.x, b4.y, b4.z, b4.w};
#pragma unroll
            for (int i = 0; i < 4; i++)
#pragma unroll
                for (int j = 0; j < 4; j++)
                    acc[i][j] = fmaf(aa[i], bb[j], acc[i][j]);
        }
    }
#pragma unroll
    for (int i = 0; i < 4; i++) {
        size_t o = (size_t)(bm + ty * 4 + i) * N + bn + tx * 4;
        float4 r = {acc[i][0], acc[i][1], acc[i][2], acc[i][3]};
        if (EPI == 1) {
            r.x = 1.f / (1.f + __expf(-r.x)); r.y = 1.f / (1.f + __expf(-r.y));
            r.z = 1.f / (1.f + __expf(-r.z)); r.w = 1.f / (1.f + __expf(-r.w));
        } else if (EPI == 2) {
            float t;
            t = fmaxf(r.x, 0.f); r.x = t * t;
            t = fmaxf(r.y, 0.f); r.y = t * t;
            t = fmaxf(r.z, 0.f); r.z = t * t;
            t = fmaxf(r.w, 0.f); r.w = t * t;
        } else if (EPI == 3) {
            float4 a0 = *(const float4*)(e0 + o);
            float4 a1 = *(const float4*)(e1 + o);
            r.x = fmaf(a1.x, r.x, a0.x); r.y = fmaf(a1.y, r.y, a0.y);
            r.z = fmaf(a1.z, r.z, a0.z); r.w = fmaf(a1.w, r.w, a0.w);
        }
        *(float4*)(out + o) = r;
    }
}

// ---------------- WKV forward checkpoint scan ----------------
// One thread per (b,c). Stores exclusive-prefix state at each chunk start.
// chk layout: [3][NCHK][BC] planes (a, b, m).
__global__ __launch_bounds__(256) void wkv_fwd_chk(const float* __restrict__ k,
    const float* __restrict__ v, const float* __restrict__ decay, float* __restrict__ chk)
{
    int idx = blockIdx.x * blockDim.x + threadIdx.x; // 0..BC-1
    int b = idx / Cv, c = idx % Cv;
    float w = decay[c] * (1.f / (float)Tv);
    float a = 0.f, bb = 0.f, m = -1e38f;
    size_t base = (size_t)b * Tv * Cv + c;
    for (int ci = 0; ci < NCHK; ci++) {
        chk[(size_t)0 * NCHK * BC + (size_t)ci * BC + idx] = a;
        chk[(size_t)1 * NCHK * BC + (size_t)ci * BC + idx] = bb;
        chk[(size_t)2 * NCHK * BC + (size_t)ci * BC + idx] = m;
        for (int tl = 0; tl < Lc; tl++) {
            size_t off = base + (size_t)(ci * Lc + tl) * Cv;
            float kt = k[off], vt = v[off];
            float mm = fmaxf(m + w, kt);
            float e1 = __expf(m + w - mm);
            float e2 = __expf(kt - mm);
            a = e1 * a + e2 * vt;
            bb = e1 * bb + e2;
            m = mm;
        }
    }
}

// ---------------- WKV combine ----------------
// Per thread: walk chunks last->first; recompute fwd prefix states for the
// chunk into fbuf (planes [3][Lc][BC]); then descending-t combine with the
// live suffix carry. y is written OVER k (safe: same thread reads k/v at off
// before writing y at off; each thread owns its channel).
__global__ __launch_bounds__(256) void wkv_combine(float* __restrict__ k,
    const float* __restrict__ v, const float* __restrict__ decay,
    const float* __restrict__ first, const float* __restrict__ chk,
    float* __restrict__ fbuf)
{
    int idx = blockIdx.x * blockDim.x + threadIdx.x;
    int b = idx / Cv, c = idx % Cv;
    float w = decay[c] * (1.f / (float)Tv);
    float u = first[c] * (1.f / (float)Tv);
    float sa = 0.f, sb = 0.f, sm = -1e38f;   // suffix carry (exclusive)
    size_t base = (size_t)b * Tv * Cv + c;
    float* fa = fbuf;
    float* fb = fbuf + (size_t)Lc * BC;
    float* fm = fbuf + (size_t)2 * Lc * BC;
    for (int ci = NCHK - 1; ci >= 0; ci--) {
        float a0 = chk[(size_t)0 * NCHK * BC + (size_t)ci * BC + idx];
        float b0 = chk[(size_t)1 * NCHK * BC + (size_t)ci * BC + idx];
        float m0 = chk[(size_t)2 * NCHK * BC + (size_t)ci * BC + idx];
        // ascending: recompute exclusive-prefix states for this chunk
        for (int tl = 0; tl < Lc; tl++) {
            size_t off = base + (size_t)(ci * Lc + tl) * Cv;
            fa[(size_t)tl * BC + idx] = a0;
            fb[(size_t)tl * BC + idx] = b0;
            fm[(size_t)tl * BC + idx] = m0;
            float kt = k[off], vt = v[off];
            float mm = fmaxf(m0 + w, kt);
            float e1 = __expf(m0 + w - mm);
            float e2 = __expf(kt - mm);
            a0 = e1 * a0 + e2 * vt;
            b0 = e1 * b0 + e2;
            m0 = mm;
        }
        // descending: combine + advance suffix
        for (int tl = Lc - 1; tl >= 0; tl--) {
            size_t off = base + (size_t)(ci * Lc + tl) * Cv;
            float kt = k[off], vt = v[off];
            float aft = fa[(size_t)tl * BC + idx];
            float bft = fb[(size_t)tl * BC + idx];
            float mft = fm[(size_t)tl * BC + idx];
            float kk = kt + u;
            float M = fmaxf(fmaxf(mft, sm), kk);
            float ef = __expf(mft - M);
            float eb = __expf(sm - M);
            float ec = __expf(kk - M);
            float num = ef * aft + eb * sa + ec * vt;
            float den = ef * bft + eb * sb + ec;
            k[off] = num / den;                 // y over k
            float mm = fmaxf(sm + w, kt);
            float e1 = __expf(sm + w - mm);
            float e2 = __expf(kt - mm);
            sa = e1 * sa + e2 * vt;
            sb = e1 * sb + e2;
            sm = mm;
        }
    }
}

__global__ __launch_bounds__(256) void fill_signal(float* __restrict__ out, int n, float val)
{
    int i = blockIdx.x * 256 + threadIdx.x;
    if (i < n) out[i] = val;
}

extern "C" void kernel_launch(void* const* d_in, const int* in_sizes, int n_in,
                              void* d_out, int out_size, void* d_ws, size_t ws_size,
                              hipStream_t stream)
{
    const float* x     = (const float*)d_in[0];
    const float* ln1_w = (const float*)d_in[1];
    const float* ln1_b = (const float*)d_in[2];
    const float* ln2_w = (const float*)d_in[3];
    const float* ln2_b = (const float*)d_in[4];
    const float* decay = (const float*)d_in[5];
    const float* first = (const float*)d_in[6];
    const float* Wk_a  = (const float*)d_in[7];
    const float* Wv_a  = (const float*)d_in[8];
    const float* Wr_a  = (const float*)d_in[9];
    const float* Wo_a  = (const float*)d_in[10];
    const float* Wk_f  = (const float*)d_in[11];
    const float* Wv_f  = (const float*)d_in[12];
    const float* Wr_f  = (const float*)d_in[13];
    float* out = (float*)d_out;

    const size_t NC = (size_t)BT * Cv;               // 12,582,912 floats
    const size_t KF = (size_t)2048 * Hv;             // 6,291,456 floats (FFN chunk)
    const size_t FB = (size_t)3 * Lc * BC;           // 2,359,296 floats
    const size_t CK = (size_t)3 * NCHK * BC;         // 294,912 floats
    const size_t need = (3 * NC + KF + FB + CK) * sizeof(float); // ~187 MB

    if (ws_size < need) {
        // Diagnostic: fail validation with absmax ~= ws_size in MB.
        fill_signal<<<(int)((NC + 255) / 256), 256, 0, stream>>>(out, (int)NC, (float)(ws_size >> 20));
        return;
    }

    float* ws  = (float*)d_ws;
    float* s0  = ws;              // h, later h2
    float* s1  = ws + NC;         // k -> y (in-place) -> gate
    float* s2  = ws + 2 * NC;     // v -> x1
    float* kfb = ws + 3 * NC;     // FFN activation chunk
    float* fbf = kfb + KF;        // WKV chunk-recompute buffer
    float* chk = fbf + FB;        // WKV checkpoints
    float* sr  = out;             // sigmoid(r) parked in d_out until FFN writes

    dim3 blk(256);
    dim3 gC(BT / 64, Cv / 64);     // (256, 12)
    dim3 gCh(2048 / 64, Cv / 64);  // (32, 12)
    dim3 gHh(2048 / 64, Hv / 64);  // (32, 48)

    // 1. h = LN1(x)
    ln_kernel<<<BT, blk, 0, stream>>>(x, ln1_w, ln1_b, s0);
    // 2-4. k, v, sr
    gemm_nt<0><<<gC, blk, 0, stream>>>(s0, Wk_a, s1, BT, Cv, Cv, nullptr, nullptr);
    gemm_nt<0><<<gC, blk, 0, stream>>>(s0, Wv_a, s2, BT, Cv, Cv, nullptr, nullptr);
    gemm_nt<1><<<gC, blk, 0, stream>>>(s0, Wr_a, sr, BT, Cv, Cv, nullptr, nullptr);
    // 5-6. bidirectional WKV (y written over k in s1)
    wkv_fwd_chk<<<BC / 256, blk, 0, stream>>>(s1, s2, decay, chk);
    wkv_combine<<<BC / 256, blk, 0, stream>>>(s1, s2, decay, first, chk, fbf);
    // 7. x1 = x + sr * (y @ Wo^T)  -> s2
    gemm_nt<3><<<gC, blk, 0, stream>>>(s1, Wo_a, s2, BT, Cv, Cv, x, sr);
    // 8. h2 = LN2(x1) -> s0
    ln_kernel<<<BT, blk, 0, stream>>>(s2, ln2_w, ln2_b, s0);
    // 9. gate = sigmoid(h2 @ Wr_f^T) -> s1
    gemm_nt<1><<<gC, blk, 0, stream>>>(s0, Wr_f, s1, BT, Cv, Cv, nullptr, nullptr);
    // 10. FFN in 8 chunks of 2048 rows (kf chunk kept in kfb)
    for (int j = 0; j < 8; j++) {
        size_t ro = (size_t)j * 2048;
        gemm_nt<2><<<gHh, blk, 0, stream>>>(s0 + ro * Cv, Wk_f, kfb, 2048, Hv, Cv, nullptr, nullptr);
        gemm_nt<3><<<gCh, blk, 0, stream>>>(kfb, Wv_f, out + ro * Cv, 2048, Cv, Hv,
                                            s2 + ro * Cv, s1 + ro * Cv);
    }
}

// Round 3
// 1041.295 us; speedup vs baseline: 5.0543x; 5.0543x over previous
//
#include <hip/hip_runtime.h>
#include <math.h>

typedef unsigned short u16;
typedef short s8v __attribute__((ext_vector_type(8)));   // 8 bf16 (4 VGPRs)
typedef float f4v __attribute__((ext_vector_type(4)));   // 4 fp32 acc

constexpr int Bv = 8, Tv = 2048, Cv = 768, Hv = 3072;
constexpr int BT = Bv * Tv;       // 16384 tokens
constexpr int BC = Bv * Cv;       // 6144 channels
constexpr int Lc = 128;           // WKV chunk length
constexpr int NCHK = Tv / Lc;     // 16 chunks

__device__ __forceinline__ float b2f(u16 x) { return __uint_as_float(((unsigned)x) << 16); }
__device__ __forceinline__ u16 f2b(float f) {
    unsigned u = __float_as_uint(f);
    return (u16)((u + 0x7fffu + ((u >> 16) & 1u)) >> 16);   // RNE
}

#define GLOAD_LDS(g, l) __builtin_amdgcn_global_load_lds( \
    (const __attribute__((address_space(1))) void*)(g),    \
    (__attribute__((address_space(3))) void*)(l), 16, 0, 0)

// ---------------- LayerNorm fp32 -> bf16 ----------------
__global__ __launch_bounds__(256) void ln_bf16(const float* __restrict__ x,
    const float* __restrict__ w, const float* __restrict__ b, u16* __restrict__ out)
{
    __shared__ float sh[8];
    int row = blockIdx.x;
    const float* xr = x + (size_t)row * Cv;
    float vals[3];
    float s = 0.f, s2 = 0.f;
#pragma unroll
    for (int i = 0; i < 3; i++) {
        float t = xr[threadIdx.x + 256 * i];
        vals[i] = t; s += t; s2 += t * t;
    }
#pragma unroll
    for (int off = 32; off > 0; off >>= 1) {
        s  += __shfl_down(s, off);
        s2 += __shfl_down(s2, off);
    }
    int wid = threadIdx.x >> 6;
    if ((threadIdx.x & 63) == 0) { sh[wid] = s; sh[4 + wid] = s2; }
    __syncthreads();
    if (threadIdx.x == 0) {
        sh[0] = sh[0] + sh[1] + sh[2] + sh[3];
        sh[4] = sh[4] + sh[5] + sh[6] + sh[7];
    }
    __syncthreads();
    float mean = sh[0] * (1.f / Cv);
    float var  = sh[4] * (1.f / Cv) - mean * mean;
    float rstd = rsqrtf(var + 1e-5f);
    u16* orow = out + (size_t)row * Cv;
#pragma unroll
    for (int i = 0; i < 3; i++) {
        int j = threadIdx.x + 256 * i;
        orow[j] = f2b((vals[i] - mean) * rstd * w[j] + b[j]);
    }
}

// ---------------- fp32 -> bf16 weight conversion ----------------
__global__ __launch_bounds__(256) void cvt_f2b(const float* __restrict__ s,
    u16* __restrict__ d, int n4)
{
    int i = blockIdx.x * 256 + threadIdx.x;
    if (i < n4) {
        float4 f = *(const float4*)(s + (size_t)i * 4);
        uint2 p;
        p.x = (unsigned)f2b(f.x) | ((unsigned)f2b(f.y) << 16);
        p.y = (unsigned)f2b(f.z) | ((unsigned)f2b(f.w) << 16);
        *(uint2*)(d + (size_t)i * 4) = p;
    }
}

// ---------------- bf16 MFMA GEMM: out = A @ W^T (+ epilogue) ----------------
// A: M x K bf16 row-major.  W: N x K bf16 row-major.  M,N % 128 == 0, K % 32 == 0.
// 128x128 tile, BK=32, 256 threads = 4 waves (2x2), 16x16x32 MFMA, 4x4 frags/wave.
// EPI: 0 none->bf16, 1 sigmoid->bf16, 2 relu^2->bf16, 3 f32 out=e0+b2f(e1)*acc, 4 f32 out=e0+acc
template<int EPI>
__global__ __launch_bounds__(256) void gemm_bf16(const u16* __restrict__ A,
    const u16* __restrict__ W, void* __restrict__ outv, int M, int N, int K,
    const float* __restrict__ e0, const u16* __restrict__ e1)
{
    __shared__ u16 As[128 * 32];
    __shared__ u16 Bs[128 * 32];
    const int tid = threadIdx.x;
    const int wid = tid >> 6, lane = tid & 63;
    const int bm = blockIdx.x * 128, bn = blockIdx.y * 128;
    const int wr = wid >> 1, wc = wid & 1;             // 2x2 wave grid, 64x64 each
    const int sr_ = tid >> 2, sk = (tid & 3) << 3;     // staging: row 0..63, k-sub 0/8/16/24
    const u16* gA0 = A + (size_t)(bm + sr_) * K + sk;
    const u16* gA1 = A + (size_t)(bm + 64 + sr_) * K + sk;
    const u16* gB0 = W + (size_t)(bn + sr_) * K + sk;
    const u16* gB1 = W + (size_t)(bn + 64 + sr_) * K + sk;
    u16* lA0 = As + wid * 512;          // wave-uniform LDS bases (lane*16B added by HW)
    u16* lA1 = As + 2048 + wid * 512;
    u16* lB0 = Bs + wid * 512;
    u16* lB1 = Bs + 2048 + wid * 512;
    const int lr_ = lane & 15, lk_ = (lane >> 4) << 3; // fragment row / k-offset
    f4v acc[4][4] = {};
    for (int k0 = 0; k0 < K; k0 += 32) {
        GLOAD_LDS(gA0 + k0, lA0);
        GLOAD_LDS(gA1 + k0, lA1);
        GLOAD_LDS(gB0 + k0, lB0);
        GLOAD_LDS(gB1 + k0, lB1);
        __syncthreads();               // compiler drains vmcnt(0) before barrier
        s8v af[4], bfr[4];
#pragma unroll
        for (int i = 0; i < 4; i++) {
            af[i]  = *(const s8v*)(As + ((wr * 64 + i * 16 + lr_) * 32 + lk_));
            bfr[i] = *(const s8v*)(Bs + ((wc * 64 + i * 16 + lr_) * 32 + lk_));
        }
#pragma unroll
        for (int mi = 0; mi < 4; mi++)
#pragma unroll
            for (int ni = 0; ni < 4; ni++)
                acc[mi][ni] = __builtin_amdgcn_mfma_f32_16x16x32_bf16(
                    af[mi], bfr[ni], acc[mi][ni], 0, 0, 0);
        __syncthreads();               // protect LDS from next iteration's stores
    }
    // epilogue: D row=(lane>>4)*4+i, col=lane&15 within each 16x16 fragment
    const int r0 = bm + wr * 64 + ((lane >> 4) << 2);
    const int c0 = bn + wc * 64 + lr_;
#pragma unroll
    for (int mi = 0; mi < 4; mi++)
#pragma unroll
        for (int ni = 0; ni < 4; ni++)
#pragma unroll
            for (int i = 0; i < 4; i++) {
                size_t o = (size_t)(r0 + mi * 16 + i) * N + (c0 + ni * 16);
                float r = acc[mi][ni][i];
                if (EPI == 1) r = 1.f / (1.f + __expf(-r));
                else if (EPI == 2) { float t = fmaxf(r, 0.f); r = t * t; }
                if (EPI == 3)      ((float*)outv)[o] = fmaf(b2f(e1[o]), r, e0[o]);
                else if (EPI == 4) ((float*)outv)[o] = e0[o] + r;
                else               ((u16*)outv)[o] = f2b(r);
            }
}

// ---------------- WKV helpers ----------------
__device__ __forceinline__ void wkv_step(float& a, float& b, float& m,
                                         float w, float kt, float vt)
{
    float mm = fmaxf(m + w, kt);
    float e1 = __expf(m + w - mm);
    float e2 = __expf(kt - mm);
    a = e1 * a + e2 * vt;
    b = e1 * b + e2;
    m = mm;
}
__device__ __forceinline__ void wkv_merge(float& a, float& b, float& m,
                                          float shift, float a2, float b2, float m2)
{
    float ms = m + shift;
    float mm = fmaxf(ms, m2);
    float e1 = __expf(ms - mm);
    float e2 = __expf(m2 - mm);
    a = e1 * a + e2 * a2;
    b = e1 * b + e2 * b2;
    m = mm;
}

// ---------------- WKV pass 1: per-chunk fwd/bwd summaries ----------------
// thread e -> (chunk ci = e/BC, channel idx = e%BC). sums: [6 planes][NCHK][BC]
__global__ __launch_bounds__(256) void wkv_pass1(const u16* __restrict__ k,
    const u16* __restrict__ v, const float* __restrict__ decay, float* __restrict__ sums)
{
    int e = blockIdx.x * 256 + threadIdx.x;
    int idx = e % BC, ci = e / BC;
    int b = idx / Cv, c = idx % Cv;
    float w = decay[c] * (1.f / (float)Tv);
    size_t base = (size_t)b * Tv * Cv + c + (size_t)ci * Lc * Cv;
    const size_t P = (size_t)NCHK * BC;
    size_t so = (size_t)ci * BC + idx;
    float a = 0.f, bb = 0.f, m = -1e38f;
    for (int t = 0; t < Lc; t++) {
        size_t off = base + (size_t)t * Cv;
        wkv_step(a, bb, m, w, b2f(k[off]), b2f(v[off]));
    }
    sums[0 * P + so] = a; sums[1 * P + so] = bb; sums[2 * P + so] = m;
    a = 0.f; bb = 0.f; m = -1e38f;
    for (int t = Lc - 1; t >= 0; t--) {
        size_t off = base + (size_t)t * Cv;
        wkv_step(a, bb, m, w, b2f(k[off]), b2f(v[off]));
    }
    sums[3 * P + so] = a; sums[4 * P + so] = bb; sums[5 * P + so] = m;
}

// ---------------- WKV pass 2: scan chunk summaries -> exclusive checkpoints ----------------
// chks: [6 planes][NCHK][BC]: 0..2 fwd-prefix (a,b,m), 3..5 bwd-suffix (a,b,m)
__global__ __launch_bounds__(256) void wkv_pass2(const float* __restrict__ decay,
    const float* __restrict__ sums, float* __restrict__ chks)
{
    int idx = blockIdx.x * 256 + threadIdx.x;   // 0..BC-1
    int c = idx % Cv;
    float shift = decay[c] * (1.f / (float)Tv) * (float)Lc;
    const size_t P = (size_t)NCHK * BC;
    float a = 0.f, bb = 0.f, m = -1e38f;
    for (int ci = 0; ci < NCHK; ci++) {
        size_t so = (size_t)ci * BC + idx;
        chks[0 * P + so] = a; chks[1 * P + so] = bb; chks[2 * P + so] = m;
        wkv_merge(a, bb, m, shift, sums[0 * P + so], sums[1 * P + so], sums[2 * P + so]);
    }
    a = 0.f; bb = 0.f; m = -1e38f;
    for (int ci = NCHK - 1; ci >= 0; ci--) {
        size_t so = (size_t)ci * BC + idx;
        chks[3 * P + so] = a; chks[4 * P + so] = bb; chks[5 * P + so] = m;
        wkv_merge(a, bb, m, shift, sums[3 * P + so], sums[4 * P + so], sums[5 * P + so]);
    }
}

// ---------------- WKV pass 3: per-chunk combine, writes y*sr over k ----------------
__global__ __launch_bounds__(256) void wkv_pass3(u16* __restrict__ k,
    const u16* __restrict__ v, const u16* __restrict__ sr,
    const float* __restrict__ decay, const float* __restrict__ first,
    const float* __restrict__ chks)
{
    int e = blockIdx.x * 256 + threadIdx.x;
    int idx = e % BC, ci = e / BC;
    int b = idx / Cv, c = idx % Cv;
    float w = decay[c] * (1.f / (float)Tv);
    float u = first[c] * (1.f / (float)Tv);
    const size_t P = (size_t)NCHK * BC;
    size_t so = (size_t)ci * BC + idx;
    size_t base = (size_t)b * Tv * Cv + c + (size_t)ci * Lc * Cv;
    // backward boundary walk: record s(16*si+15) for si=7..0
    float sa = chks[3 * P + so], sb2 = chks[4 * P + so], sm = chks[5 * P + so];
    float Ba[8], Bb[8], Bm[8];
#pragma unroll
    for (int si = 7; si >= 0; si--) {
        Ba[si] = sa; Bb[si] = sb2; Bm[si] = sm;
        for (int j = 15; j >= 0; j--) {
            size_t off = base + (size_t)(si * 16 + j) * Cv;
            wkv_step(sa, sb2, sm, w, b2f(k[off]), b2f(v[off]));
        }
    }
    // forward walk with 16-step register recompute of suffix states
    float fa = chks[0 * P + so], fb2 = chks[1 * P + so], fm = chks[2 * P + so];
#pragma unroll
    for (int si = 0; si < 8; si++) {
        float lk[16], lv[16], la[16], lb[16], lm[16];
        float ta = Ba[si], tb = Bb[si], tm = Bm[si];
#pragma unroll
        for (int j = 15; j >= 0; j--) {
            size_t off = base + (size_t)(si * 16 + j) * Cv;
            lk[j] = b2f(k[off]); lv[j] = b2f(v[off]);
            la[j] = ta; lb[j] = tb; lm[j] = tm;   // exclusive suffix s(t)
            wkv_step(ta, tb, tm, w, lk[j], lv[j]);
        }
#pragma unroll
        for (int j = 0; j < 16; j++) {
            float kk = lk[j] + u;
            float M  = fmaxf(fmaxf(fm, lm[j]), kk);
            float ef = __expf(fm - M);
            float eb = __expf(lm[j] - M);
            float ec = __expf(kk - M);
            float num = ef * fa + eb * la[j] + ec * lv[j];
            float den = ef * fb2 + eb * lb[j] + ec;
            size_t off = base + (size_t)(si * 16 + j) * Cv;
            k[off] = f2b(b2f(sr[off]) * (num / den));   // y' = sr * y (ref: (sr*y)@Wo^T)
            wkv_step(fa, fb2, fm, w, lk[j], lv[j]);
        }
    }
}

__global__ __launch_bounds__(256) void fill_signal(float* __restrict__ out, int n, float val)
{
    int i = blockIdx.x * 256 + threadIdx.x;
    if (i < n) out[i] = val;
}

extern "C" void kernel_launch(void* const* d_in, const int* in_sizes, int n_in,
                              void* d_out, int out_size, void* d_ws, size_t ws_size,
                              hipStream_t stream)
{
    const float* x     = (const float*)d_in[0];
    const float* ln1_w = (const float*)d_in[1];
    const float* ln1_b = (const float*)d_in[2];
    const float* ln2_w = (const float*)d_in[3];
    const float* ln2_b = (const float*)d_in[4];
    const float* decay = (const float*)d_in[5];
    const float* first = (const float*)d_in[6];
    const float* Wk_a  = (const float*)d_in[7];
    const float* Wv_a  = (const float*)d_in[8];
    const float* Wr_a  = (const float*)d_in[9];
    const float* Wo_a  = (const float*)d_in[10];
    const float* Wk_f  = (const float*)d_in[11];
    const float* Wv_f  = (const float*)d_in[12];
    const float* Wr_f  = (const float*)d_in[13];
    float* out = (float*)d_out;

    const size_t NCe = (size_t)BT * Cv;        // 12,582,912
    const size_t CC  = (size_t)Cv * Cv;        // 589,824
    const size_t HC  = (size_t)Hv * Cv;        // 2,359,296
    const size_t KFC = (size_t)2048 * Hv;      // 6,291,456 (FFN chunk)
    const size_t SUM = (size_t)6 * NCHK * BC;  // 589,824

    u16* hb   = (u16*)d_ws;                    // h / h2 (bf16)
    u16* kb   = hb + NCe;                      // k -> y*sr (bf16)
    u16* vb   = kb + NCe;                      // v -> gate (bf16)
    u16* srb  = vb + NCe;                      // sigmoid(r) (bf16)
    float* x1 = (float*)(srb + NCe);           // x after attention (fp32)
    u16* kfb  = (u16*)(x1 + NCe);              // FFN activation chunk (bf16)
    u16* wKa  = kfb + KFC;                     // bf16 weights
    u16* wVa  = wKa + CC;
    u16* wRa  = wVa + CC;
    u16* wOa  = wRa + CC;
    u16* wKf  = wOa + CC;
    u16* wVf  = wKf + HC;
    u16* wRf  = wVf + HC;
    float* sums = (float*)(wRf + CC);
    float* chks = sums + SUM;
    size_t need = (size_t)((char*)(chks + SUM) - (char*)d_ws);

    if (ws_size < need) {
        fill_signal<<<(int)((NCe + 255) / 256), 256, 0, stream>>>(out, (int)NCe, (float)(ws_size >> 20));
        return;
    }

    dim3 blk(256);
    // weight conversion
    cvt_f2b<<<(int)(CC / 4 + 255) / 256, blk, 0, stream>>>(Wk_a, wKa, (int)(CC / 4));
    cvt_f2b<<<(int)(CC / 4 + 255) / 256, blk, 0, stream>>>(Wv_a, wVa, (int)(CC / 4));
    cvt_f2b<<<(int)(CC / 4 + 255) / 256, blk, 0, stream>>>(Wr_a, wRa, (int)(CC / 4));
    cvt_f2b<<<(int)(CC / 4 + 255) / 256, blk, 0, stream>>>(Wo_a, wOa, (int)(CC / 4));
    cvt_f2b<<<(int)(HC / 4 + 255) / 256, blk, 0, stream>>>(Wk_f, wKf, (int)(HC / 4));
    cvt_f2b<<<(int)(HC / 4 + 255) / 256, blk, 0, stream>>>(Wv_f, wVf, (int)(HC / 4));
    cvt_f2b<<<(int)(CC / 4 + 255) / 256, blk, 0, stream>>>(Wr_f, wRf, (int)(CC / 4));

    dim3 gC(BT / 128, Cv / 128);     // (128, 6)
    dim3 gCh(2048 / 128, Cv / 128);  // (16, 6)
    dim3 gHh(2048 / 128, Hv / 128);  // (16, 24)

    // 1. h = LN1(x)
    ln_bf16<<<BT, blk, 0, stream>>>(x, ln1_w, ln1_b, hb);
    // 2-4. k, v, sr
    gemm_bf16<0><<<gC, blk, 0, stream>>>(hb, wKa, kb, BT, Cv, Cv, nullptr, nullptr);
    gemm_bf16<0><<<gC, blk, 0, stream>>>(hb, wVa, vb, BT, Cv, Cv, nullptr, nullptr);
    gemm_bf16<1><<<gC, blk, 0, stream>>>(hb, wRa, srb, BT, Cv, Cv, nullptr, nullptr);
    // 5. bidirectional WKV (chunk-parallel); y*sr written over k
    wkv_pass1<<<(BC * NCHK) / 256, blk, 0, stream>>>(kb, vb, decay, sums);
    wkv_pass2<<<BC / 256, blk, 0, stream>>>(decay, sums, chks);
    wkv_pass3<<<(BC * NCHK) / 256, blk, 0, stream>>>(kb, vb, srb, decay, first, chks);
    // 6. x1 = x + (sr*y) @ Wo^T
    gemm_bf16<4><<<gC, blk, 0, stream>>>(kb, wOa, x1, BT, Cv, Cv, x, nullptr);
    // 7. h2 = LN2(x1)
    ln_bf16<<<BT, blk, 0, stream>>>(x1, ln2_w, ln2_b, hb);
    // 8. gate = sigmoid(h2 @ Wr_f^T)
    gemm_bf16<1><<<gC, blk, 0, stream>>>(hb, wRf, vb, BT, Cv, Cv, nullptr, nullptr);
    // 9. FFN in 8 row-chunks of 2048
    for (int j = 0; j < 8; j++) {
        size_t ro = (size_t)j * 2048;
        gemm_bf16<2><<<gHh, blk, 0, stream>>>(hb + ro * Cv, wKf, kfb, 2048, Hv, Cv, nullptr, nullptr);
        gemm_bf16<3><<<gCh, blk, 0, stream>>>(kfb, wVf, out + ro * Cv, 2048, Cv, Hv,
                                              x1 + ro * Cv, vb + ro * Cv);
    }
}

// Round 4
// 598.319 us; speedup vs baseline: 8.7964x; 1.7404x over previous
//
#include <hip/hip_runtime.h>
#include <math.h>

typedef unsigned short u16;
typedef short s8v __attribute__((ext_vector_type(8)));   // 8 bf16 (4 VGPRs)
typedef float f4v __attribute__((ext_vector_type(4)));   // 4 fp32 acc

constexpr int Bv = 8, Tv = 2048, Cv = 768, Hv = 3072;
constexpr int BT = Bv * Tv;       // 16384 tokens
constexpr int BC = Bv * Cv;       // 6144 channels
constexpr int Lc = 128;           // WKV chunk length
constexpr int NCHK = Tv / Lc;     // 16 chunks
constexpr int KVS = 2304;         // fused k|v|sr row stride

__device__ __forceinline__ float b2f(u16 x) { return __uint_as_float(((unsigned)x) << 16); }
__device__ __forceinline__ u16 f2b(float f) {
    unsigned u = __float_as_uint(f);
    return (u16)((u + 0x7fffu + ((u >> 16) & 1u)) >> 16);   // RNE
}

#define GLOAD_LDS(g, l) __builtin_amdgcn_global_load_lds( \
    (const __attribute__((address_space(1))) void*)(g),    \
    (__attribute__((address_space(3))) void*)(l), 16, 0, 0)

// ---------------- LayerNorm fp32 -> bf16 ----------------
__global__ __launch_bounds__(256) void ln_bf16(const float* __restrict__ x,
    const float* __restrict__ w, const float* __restrict__ b, u16* __restrict__ out)
{
    __shared__ float sh[8];
    int row = blockIdx.x;
    const float* xr = x + (size_t)row * Cv;
    float vals[3];
    float s = 0.f, s2 = 0.f;
#pragma unroll
    for (int i = 0; i < 3; i++) {
        float t = xr[threadIdx.x + 256 * i];
        vals[i] = t; s += t; s2 += t * t;
    }
#pragma unroll
    for (int off = 32; off > 0; off >>= 1) {
        s  += __shfl_down(s, off);
        s2 += __shfl_down(s2, off);
    }
    int wid = threadIdx.x >> 6;
    if ((threadIdx.x & 63) == 0) { sh[wid] = s; sh[4 + wid] = s2; }
    __syncthreads();
    if (threadIdx.x == 0) {
        sh[0] = sh[0] + sh[1] + sh[2] + sh[3];
        sh[4] = sh[4] + sh[5] + sh[6] + sh[7];
    }
    __syncthreads();
    float mean = sh[0] * (1.f / Cv);
    float var  = sh[4] * (1.f / Cv) - mean * mean;
    float rstd = rsqrtf(var + 1e-5f);
    u16* orow = out + (size_t)row * Cv;
#pragma unroll
    for (int i = 0; i < 3; i++) {
        int j = threadIdx.x + 256 * i;
        orow[j] = f2b((vals[i] - mean) * rstd * w[j] + b[j]);
    }
}

// ---------------- fp32 -> bf16 weight conversion ----------------
__global__ __launch_bounds__(256) void cvt_f2b(const float* __restrict__ s,
    u16* __restrict__ d, int n4)
{
    int i = blockIdx.x * 256 + threadIdx.x;
    if (i < n4) {
        float4 f = *(const float4*)(s + (size_t)i * 4);
        uint2 p;
        p.x = (unsigned)f2b(f.x) | ((unsigned)f2b(f.y) << 16);
        p.y = (unsigned)f2b(f.z) | ((unsigned)f2b(f.w) << 16);
        *(uint2*)(d + (size_t)i * 4) = p;
    }
}

// ---------------- bf16 MFMA GEMM: out = A @ W^T (+ epilogue) ----------------
// A: M x K bf16, row stride lda.  W: N x K bf16, row stride ldw.
// grid.x = M/128, grid.y = N/128.  K % 32 == 0.
// 128x128 tile, BK=32, 4 waves (2x2), 16x16x32 MFMA, 4x4 frags/wave.
// EPI 0: bf16 out; sigmoid applied when bn >= sigoff
// EPI 2: bf16 out = relu(acc)^2
// EPI 3: f32 out = e0 + b2f(e1) * acc
// EPI 4: f32 out = e0 + acc
template<int EPI>
__global__ __launch_bounds__(256) void gemm_bf16(const u16* __restrict__ A,
    const u16* __restrict__ W, void* __restrict__ outv, int K,
    int lda, int ldw, int ldc, int sigoff,
    const float* __restrict__ e0, const u16* __restrict__ e1)
{
    __shared__ u16 As[128 * 32];
    __shared__ u16 Bs[128 * 32];
    const int tid = threadIdx.x;
    const int wid = tid >> 6, lane = tid & 63;
    const int bm = blockIdx.x * 128, bn = blockIdx.y * 128;
    const int wr = wid >> 1, wc = wid & 1;             // 2x2 wave grid, 64x64 each
    const int sr_ = tid >> 2, sk = (tid & 3) << 3;     // staging: row 0..63, k-sub 0/8/16/24
    const u16* gA0 = A + (size_t)(bm + sr_) * lda + sk;
    const u16* gA1 = A + (size_t)(bm + 64 + sr_) * lda + sk;
    const u16* gB0 = W + (size_t)(bn + sr_) * ldw + sk;
    const u16* gB1 = W + (size_t)(bn + 64 + sr_) * ldw + sk;
    u16* lA0 = As + wid * 512;          // wave-uniform LDS bases (lane*16B added by HW)
    u16* lA1 = As + 2048 + wid * 512;
    u16* lB0 = Bs + wid * 512;
    u16* lB1 = Bs + 2048 + wid * 512;
    const int lr_ = lane & 15, lk_ = (lane >> 4) << 3; // fragment row / k-offset
    f4v acc[4][4] = {};
    for (int k0 = 0; k0 < K; k0 += 32) {
        GLOAD_LDS(gA0 + k0, lA0);
        GLOAD_LDS(gA1 + k0, lA1);
        GLOAD_LDS(gB0 + k0, lB0);
        GLOAD_LDS(gB1 + k0, lB1);
        __syncthreads();
        s8v af[4], bfr[4];
#pragma unroll
        for (int i = 0; i < 4; i++) {
            af[i]  = *(const s8v*)(As + ((wr * 64 + i * 16 + lr_) * 32 + lk_));
            bfr[i] = *(const s8v*)(Bs + ((wc * 64 + i * 16 + lr_) * 32 + lk_));
        }
#pragma unroll
        for (int mi = 0; mi < 4; mi++)
#pragma unroll
            for (int ni = 0; ni < 4; ni++)
                acc[mi][ni] = __builtin_amdgcn_mfma_f32_16x16x32_bf16(
                    af[mi], bfr[ni], acc[mi][ni], 0, 0, 0);
        __syncthreads();
    }
    // epilogue: D row=(lane>>4)*4+i, col=lane&15 within each 16x16 fragment
    const int r0 = bm + wr * 64 + ((lane >> 4) << 2);
    const int c0 = bn + wc * 64 + lr_;
    const bool sig = (EPI == 0) && (bn >= sigoff);
#pragma unroll
    for (int mi = 0; mi < 4; mi++)
#pragma unroll
        for (int ni = 0; ni < 4; ni++)
#pragma unroll
            for (int i = 0; i < 4; i++) {
                size_t o = (size_t)(r0 + mi * 16 + i) * ldc + (c0 + ni * 16);
                float r = acc[mi][ni][i];
                if (EPI == 0) {
                    if (sig) r = 1.f / (1.f + __expf(-r));
                    ((u16*)outv)[o] = f2b(r);
                } else if (EPI == 2) {
                    float t = fmaxf(r, 0.f);
                    ((u16*)outv)[o] = f2b(t * t);
                } else if (EPI == 3) {
                    ((float*)outv)[o] = fmaf(b2f(e1[o]), r, e0[o]);
                } else if (EPI == 4) {
                    ((float*)outv)[o] = e0[o] + r;
                }
            }
}

// ---------------- WKV helpers ----------------
__device__ __forceinline__ void wkv_step(float& a, float& b, float& m,
                                         float w, float kt, float vt)
{
    float mm = fmaxf(m + w, kt);
    float e1 = __expf(m + w - mm);
    float e2 = __expf(kt - mm);
    a = e1 * a + e2 * vt;
    b = e1 * b + e2;
    m = mm;
}
__device__ __forceinline__ void wkv_merge(float& a, float& b, float& m,
                                          float shift, float a2, float b2, float m2)
{
    float ms = m + shift;
    float mm = fmaxf(ms, m2);
    float e1 = __expf(ms - mm);
    float e2 = __expf(m2 - mm);
    a = e1 * a + e2 * a2;
    b = e1 * b + e2 * b2;
    m = mm;
}

// ---------------- WKV pass 1: per-chunk fwd/bwd summaries ----------------
// kvs: k at col c, v at col c+768 of row (b*Tv+t), stride KVS.
__global__ __launch_bounds__(256) void wkv_pass1(const u16* __restrict__ kvs,
    const float* __restrict__ decay, float* __restrict__ sums)
{
    int e = blockIdx.x * 256 + threadIdx.x;
    int idx = e % BC, ci = e / BC;
    int b = idx / Cv, c = idx % Cv;
    float w = decay[c] * (1.f / (float)Tv);
    size_t base = ((size_t)b * Tv + (size_t)ci * Lc) * KVS + c;
    const size_t P = (size_t)NCHK * BC;
    size_t so = (size_t)ci * BC + idx;
    float a = 0.f, bb = 0.f, m = -1e38f;
    for (int t = 0; t < Lc; t++) {
        size_t off = base + (size_t)t * KVS;
        wkv_step(a, bb, m, w, b2f(kvs[off]), b2f(kvs[off + 768]));
    }
    sums[0 * P + so] = a; sums[1 * P + so] = bb; sums[2 * P + so] = m;
    a = 0.f; bb = 0.f; m = -1e38f;
    for (int t = Lc - 1; t >= 0; t--) {
        size_t off = base + (size_t)t * KVS;
        wkv_step(a, bb, m, w, b2f(kvs[off]), b2f(kvs[off + 768]));
    }
    sums[3 * P + so] = a; sums[4 * P + so] = bb; sums[5 * P + so] = m;
}

// ---------------- WKV pass 2: scan chunk summaries -> exclusive checkpoints ----------------
__global__ __launch_bounds__(256) void wkv_pass2(const float* __restrict__ decay,
    const float* __restrict__ sums, float* __restrict__ chks)
{
    int idx = blockIdx.x * 256 + threadIdx.x;   // 0..BC-1
    int c = idx % Cv;
    float shift = decay[c] * (1.f / (float)Tv) * (float)Lc;
    const size_t P = (size_t)NCHK * BC;
    float a = 0.f, bb = 0.f, m = -1e38f;
    for (int ci = 0; ci < NCHK; ci++) {
        size_t so = (size_t)ci * BC + idx;
        chks[0 * P + so] = a; chks[1 * P + so] = bb; chks[2 * P + so] = m;
        wkv_merge(a, bb, m, shift, sums[0 * P + so], sums[1 * P + so], sums[2 * P + so]);
    }
    a = 0.f; bb = 0.f; m = -1e38f;
    for (int ci = NCHK - 1; ci >= 0; ci--) {
        size_t so = (size_t)ci * BC + idx;
        chks[3 * P + so] = a; chks[4 * P + so] = bb; chks[5 * P + so] = m;
        wkv_merge(a, bb, m, shift, sums[3 * P + so], sums[4 * P + so], sums[5 * P + so]);
    }
}

// ---------------- WKV pass 3: per-chunk combine, writes y*sr over k slot ----------------
__global__ __launch_bounds__(256) void wkv_pass3(u16* __restrict__ kvs,
    const float* __restrict__ decay, const float* __restrict__ first,
    const float* __restrict__ chks)
{
    int e = blockIdx.x * 256 + threadIdx.x;
    int idx = e % BC, ci = e / BC;
    int b = idx / Cv, c = idx % Cv;
    float w = decay[c] * (1.f / (float)Tv);
    float u = first[c] * (1.f / (float)Tv);
    const size_t P = (size_t)NCHK * BC;
    size_t so = (size_t)ci * BC + idx;
    size_t base = ((size_t)b * Tv + (size_t)ci * Lc) * KVS + c;
    // backward boundary walk: record suffix state at sub-chunk ends
    float sa = chks[3 * P + so], sb2 = chks[4 * P + so], sm = chks[5 * P + so];
    float Ba[8], Bb[8], Bm[8];
#pragma unroll
    for (int si = 7; si >= 0; si--) {
        Ba[si] = sa; Bb[si] = sb2; Bm[si] = sm;
        for (int j = 15; j >= 0; j--) {
            size_t off = base + (size_t)(si * 16 + j) * KVS;
            wkv_step(sa, sb2, sm, w, b2f(kvs[off]), b2f(kvs[off + 768]));
        }
    }
    // forward walk with 16-step register recompute of suffix states
    float fa = chks[0 * P + so], fb2 = chks[1 * P + so], fm = chks[2 * P + so];
#pragma unroll
    for (int si = 0; si < 8; si++) {
        float lk[16], lv[16], la[16], lb[16], lm[16];
        float ta = Ba[si], tb = Bb[si], tm = Bm[si];
#pragma unroll
        for (int j = 15; j >= 0; j--) {
            size_t off = base + (size_t)(si * 16 + j) * KVS;
            lk[j] = b2f(kvs[off]); lv[j] = b2f(kvs[off + 768]);
            la[j] = ta; lb[j] = tb; lm[j] = tm;   // exclusive suffix s(t)
            wkv_step(ta, tb, tm, w, lk[j], lv[j]);
        }
#pragma unroll
        for (int j = 0; j < 16; j++) {
            float kk = lk[j] + u;
            float M  = fmaxf(fmaxf(fm, lm[j]), kk);
            float ef = __expf(fm - M);
            float eb = __expf(lm[j] - M);
            float ec = __expf(kk - M);
            float num = ef * fa + eb * la[j] + ec * lv[j];
            float den = ef * fb2 + eb * lb[j] + ec;
            size_t off = base + (size_t)(si * 16 + j) * KVS;
            kvs[off] = f2b(b2f(kvs[off + 1536]) * (num / den));  // y' = sr * y
            wkv_step(fa, fb2, fm, w, lk[j], lv[j]);
        }
    }
}

__global__ __launch_bounds__(256) void fill_signal(float* __restrict__ out, int n, float val)
{
    int i = blockIdx.x * 256 + threadIdx.x;
    if (i < n) out[i] = val;
}

extern "C" void kernel_launch(void* const* d_in, const int* in_sizes, int n_in,
                              void* d_out, int out_size, void* d_ws, size_t ws_size,
                              hipStream_t stream)
{
    const float* x     = (const float*)d_in[0];
    const float* ln1_w = (const float*)d_in[1];
    const float* ln1_b = (const float*)d_in[2];
    const float* ln2_w = (const float*)d_in[3];
    const float* ln2_b = (const float*)d_in[4];
    const float* decay = (const float*)d_in[5];
    const float* first = (const float*)d_in[6];
    const float* Wk_a  = (const float*)d_in[7];
    const float* Wv_a  = (const float*)d_in[8];
    const float* Wr_a  = (const float*)d_in[9];
    const float* Wo_a  = (const float*)d_in[10];
    const float* Wk_f  = (const float*)d_in[11];
    const float* Wv_f  = (const float*)d_in[12];
    const float* Wr_f  = (const float*)d_in[13];
    float* out = (float*)d_out;

    const size_t NCe = (size_t)BT * Cv;        // 12,582,912
    const size_t CC  = (size_t)Cv * Cv;        // 589,824
    const size_t HC  = (size_t)Hv * Cv;        // 2,359,296
    const size_t SUM = (size_t)6 * NCHK * BC;  // 589,824

    u16* hb    = (u16*)d_ws;                   // h / h2 (bf16)
    u16* kvs   = hb + NCe;                     // 3*NCe: k|v|sr interleaved (stride 2304)
    float* x1  = (float*)(kvs + 3 * NCe);      // fp32 x after attention
    u16* wKVR  = (u16*)(x1 + NCe);             // bf16 weights: [Wk;Wv;Wr] 2304x768
    u16* wOa   = wKVR + 3 * CC;
    u16* wRf   = wOa + CC;
    u16* wKf   = wRf + CC;                     // 3072x768
    u16* wVf   = wKf + HC;                     // 768x3072
    float* sums = (float*)(wVf + HC);
    float* chks = sums + SUM;
    u16* kfb_full = (u16*)(chks + SUM);        // full FFN activation (only if ws fits)
    size_t need_chunk = (size_t)((char*)kfb_full - (char*)d_ws);
    size_t need_full  = need_chunk + (size_t)BT * Hv * sizeof(u16);

    if (ws_size < need_chunk) {
        fill_signal<<<(int)((NCe + 255) / 256), 256, 0, stream>>>(out, (int)NCe, (float)(ws_size >> 20));
        return;
    }
    const bool full = (ws_size >= need_full);

    // overlays into dead kvs region (after Wo-GEMM):
    u16* gate = kvs;            // NCe
    u16* kfb_c = kvs + NCe;     // 2*NCe = 8192*3072 exactly (chunked FFN activation)

    dim3 blk(256);
    cvt_f2b<<<(int)(CC / 4 + 255) / 256, blk, 0, stream>>>(Wk_a, wKVR, (int)(CC / 4));
    cvt_f2b<<<(int)(CC / 4 + 255) / 256, blk, 0, stream>>>(Wv_a, wKVR + CC, (int)(CC / 4));
    cvt_f2b<<<(int)(CC / 4 + 255) / 256, blk, 0, stream>>>(Wr_a, wKVR + 2 * CC, (int)(CC / 4));
    cvt_f2b<<<(int)(CC / 4 + 255) / 256, blk, 0, stream>>>(Wo_a, wOa, (int)(CC / 4));
    cvt_f2b<<<(int)(CC / 4 + 255) / 256, blk, 0, stream>>>(Wr_f, wRf, (int)(CC / 4));
    cvt_f2b<<<(int)(HC / 4 + 255) / 256, blk, 0, stream>>>(Wk_f, wKf, (int)(HC / 4));
    cvt_f2b<<<(int)(HC / 4 + 255) / 256, blk, 0, stream>>>(Wv_f, wVf, (int)(HC / 4));

    // 1. h = LN1(x)
    ln_bf16<<<BT, blk, 0, stream>>>(x, ln1_w, ln1_b, hb);
    // 2. fused [k|v|sr] = h @ [Wk;Wv;Wr]^T  (sigmoid on cols >= 1536)
    gemm_bf16<0><<<dim3(BT / 128, KVS / 128), blk, 0, stream>>>(
        hb, wKVR, kvs, Cv, Cv, Cv, KVS, 1536, nullptr, nullptr);
    // 3. bidirectional WKV (chunk-parallel); y*sr written over k slot
    wkv_pass1<<<(BC * NCHK) / 256, blk, 0, stream>>>(kvs, decay, sums);
    wkv_pass2<<<BC / 256, blk, 0, stream>>>(decay, sums, chks);
    wkv_pass3<<<(BC * NCHK) / 256, blk, 0, stream>>>(kvs, decay, first, chks);
    // 4. x1 = x + (sr*y) @ Wo^T
    gemm_bf16<4><<<dim3(BT / 128, Cv / 128), blk, 0, stream>>>(
        kvs, wOa, x1, Cv, KVS, Cv, Cv, 0, x, nullptr);
    // 5. h2 = LN2(x1)
    ln_bf16<<<BT, blk, 0, stream>>>(x1, ln2_w, ln2_b, hb);
    // 6. gate = sigmoid(h2 @ Wr_f^T)  (kvs now dead -> overlay)
    gemm_bf16<0><<<dim3(BT / 128, Cv / 128), blk, 0, stream>>>(
        hb, wRf, gate, Cv, Cv, Cv, Cv, 0, nullptr, nullptr);
    // 7. FFN
    if (full) {
        gemm_bf16<2><<<dim3(BT / 128, Hv / 128), blk, 0, stream>>>(
            hb, wKf, kfb_full, Cv, Cv, Cv, Hv, 0, nullptr, nullptr);
        gemm_bf16<3><<<dim3(BT / 128, Cv / 128), blk, 0, stream>>>(
            kfb_full, wVf, out, Hv, Hv, Hv, Cv, 0, x1, gate);
    } else {
        for (int j = 0; j < 2; j++) {
            size_t ro = (size_t)j * 8192;
            gemm_bf16<2><<<dim3(8192 / 128, Hv / 128), blk, 0, stream>>>(
                hb + ro * Cv, wKf, kfb_c, Cv, Cv, Cv, Hv, 0, nullptr, nullptr);
            gemm_bf16<3><<<dim3(8192 / 128, Cv / 128), blk, 0, stream>>>(
                kfb_c, wVf, out + ro * Cv, Hv, Hv, Hv, Cv, 0, x1 + ro * Cv, gate + ro * Cv);
        }
    }
}

// Round 5
// 526.344 us; speedup vs baseline: 9.9993x; 1.1367x over previous
//
#include <hip/hip_runtime.h>
#include <math.h>

typedef unsigned short u16;
typedef short s8v __attribute__((ext_vector_type(8)));   // 8 bf16 (4 VGPRs)
typedef float f4v __attribute__((ext_vector_type(4)));   // 4 fp32 acc

constexpr int Bv = 8, Tv = 2048, Cv = 768, Hv = 3072;
constexpr int BT = Bv * Tv;       // 16384 tokens
constexpr int BC = Bv * Cv;       // 6144 channels
constexpr int Lc = 128;           // WKV chunk length
constexpr int NCHK = Tv / Lc;     // 16 chunks
constexpr int KVS = 2304;         // fused k|v|sr row stride

__device__ __forceinline__ float b2f(u16 x) { return __uint_as_float(((unsigned)x) << 16); }
__device__ __forceinline__ u16 f2b(float f) {
    unsigned u = __float_as_uint(f);
    return (u16)((u + 0x7fffu + ((u >> 16) & 1u)) >> 16);   // RNE
}

#define GLOAD_LDS(g, l) __builtin_amdgcn_global_load_lds( \
    (const __attribute__((address_space(1))) void*)(g),    \
    (__attribute__((address_space(3))) void*)(l), 16, 0, 0)
#define BAR()  __builtin_amdgcn_s_barrier()
#define SB0()  __builtin_amdgcn_sched_barrier(0)

// ---------------- LayerNorm fp32 -> bf16 ----------------
__global__ __launch_bounds__(256) void ln_bf16(const float* __restrict__ x,
    const float* __restrict__ w, const float* __restrict__ b, u16* __restrict__ out)
{
    __shared__ float sh[8];
    int row = blockIdx.x;
    const float* xr = x + (size_t)row * Cv;
    float vals[3];
    float s = 0.f, s2 = 0.f;
#pragma unroll
    for (int i = 0; i < 3; i++) {
        float t = xr[threadIdx.x + 256 * i];
        vals[i] = t; s += t; s2 += t * t;
    }
#pragma unroll
    for (int off = 32; off > 0; off >>= 1) {
        s  += __shfl_down(s, off);
        s2 += __shfl_down(s2, off);
    }
    int wid = threadIdx.x >> 6;
    if ((threadIdx.x & 63) == 0) { sh[wid] = s; sh[4 + wid] = s2; }
    __syncthreads();
    if (threadIdx.x == 0) {
        sh[0] = sh[0] + sh[1] + sh[2] + sh[3];
        sh[4] = sh[4] + sh[5] + sh[6] + sh[7];
    }
    __syncthreads();
    float mean = sh[0] * (1.f / Cv);
    float var  = sh[4] * (1.f / Cv) - mean * mean;
    float rstd = rsqrtf(var + 1e-5f);
    u16* orow = out + (size_t)row * Cv;
#pragma unroll
    for (int i = 0; i < 3; i++) {
        int j = threadIdx.x + 256 * i;
        orow[j] = f2b((vals[i] - mean) * rstd * w[j] + b[j]);
    }
}

// ---------------- fp32 -> bf16 weight conversion ----------------
__global__ __launch_bounds__(256) void cvt_f2b(const float* __restrict__ s,
    u16* __restrict__ d, int n4)
{
    int i = blockIdx.x * 256 + threadIdx.x;
    if (i < n4) {
        float4 f = *(const float4*)(s + (size_t)i * 4);
        uint2 p;
        p.x = (unsigned)f2b(f.x) | ((unsigned)f2b(f.y) << 16);
        p.y = (unsigned)f2b(f.z) | ((unsigned)f2b(f.w) << 16);
        *(uint2*)(d + (size_t)i * 4) = p;
    }
}

// ---------------- deep-pipelined bf16 MFMA GEMM: out = A @ W^T (+ epilogue) ----------------
// BM=128, BN=256, BK=64. 512 threads = 8 waves (2x4); per-wave C = 64x64 (4x4 frags).
// 3-buffer K-tile rotation in LDS (3 x 48 KiB = 144 KiB), counted vmcnt(6),
// row-XOR LDS swizzle (colbyte ^= (row&7)<<4) via pre-swizzled global source.
// grid = (M/128, N/256); K % 64 == 0.
// EPI 0: bf16 out, sigmoid when bn >= sigoff; EPI 2: bf16 relu(acc)^2;
// EPI 3: f32 out = e0 + b2f(e1)*acc; EPI 4: f32 out = e0 + acc
template<int EPI>
__global__ __launch_bounds__(512) void gemm256(const u16* __restrict__ A,
    const u16* __restrict__ W, void* __restrict__ outv, int K,
    int lda, int ldw, int ldc, int sigoff,
    const float* __restrict__ e0, const u16* __restrict__ e1)
{
    extern __shared__ u16 lds[];               // 3 * 24576 u16
    const int tid = threadIdx.x;
    const int wv = tid >> 6, l = tid & 63;
    const int bm = blockIdx.x * 128, bn = blockIdx.y * 256;
    const int wr = wv >> 2, wc = wv & 3;       // 2x4 wave grid
    // staging: lane l covers row (l>>3) of an 8-row block, 16B chunk (l&7),
    // source column pre-swizzled so LDS[row][c] = G[row][c ^ ((row&7)<<4)]
    const int srow  = l >> 3;
    const int scolu = ((l & 7) ^ srow) << 3;   // u16 offset within 64-u16 row
    const u16* pA0 = A + (size_t)(bm +       wv * 8 + srow) * lda + scolu;
    const u16* pA1 = A + (size_t)(bm +  64 + wv * 8 + srow) * lda + scolu;
    const u16* pB0 = W + (size_t)(bn +       wv * 8 + srow) * ldw + scolu;
    const u16* pB1 = W + (size_t)(bn +  64 + wv * 8 + srow) * ldw + scolu;
    const u16* pB2 = W + (size_t)(bn + 128 + wv * 8 + srow) * ldw + scolu;
    const u16* pB3 = W + (size_t)(bn + 192 + wv * 8 + srow) * ldw + scolu;
    const int lA0 = wv * 512, lA1 = 4096 + wv * 512;      // A: 128x64 = 8192 u16
    const int lB0 = 8192 + wv * 512,  lB1 = 12288 + wv * 512;
    const int lB2 = 16384 + wv * 512, lB3 = 20480 + wv * 512;
#define STG_H0(kt, b) { const size_t kc = (size_t)(kt) * 64; const int o = (b) * 24576; \
    GLOAD_LDS(pA0 + kc, lds + o + lA0); GLOAD_LDS(pA1 + kc, lds + o + lA1); \
    GLOAD_LDS(pB0 + kc, lds + o + lB0); }
#define STG_H1(kt, b) { const size_t kc = (size_t)(kt) * 64; const int o = (b) * 24576; \
    GLOAD_LDS(pB1 + kc, lds + o + lB1); GLOAD_LDS(pB2 + kc, lds + o + lB2); \
    GLOAD_LDS(pB3 + kc, lds + o + lB3); }
    // fragment read offsets (u16), swizzled: col ^ ((row&7)<<4) bytes
    const int fswz  = (l & 7) << 3;                        // (row&7)<<4 bytes -> u16
    const int colu0 = (((l >> 4) << 3)) ^ fswz;            // kk=0
    const int colu1 = (32 + ((l >> 4) << 3)) ^ fswz;       // kk=1
    const int aoff  = (wr * 64 + (l & 15)) * 64;
    const int boff  = 8192 + (wc * 64 + (l & 15)) * 64;
    f4v acc[4][4] = {};
    const int NKT = K >> 6;
    // prologue: stage tiles 0,1 into buffers 0,1
    STG_H0(0, 0); STG_H1(0, 0);
    STG_H0(1, 1); STG_H1(1, 1);
    asm volatile("s_waitcnt vmcnt(6)" ::: "memory");
    BAR(); SB0();
    int cur = 0;
    for (int kt = 0; kt < NKT; ++kt) {
        const int co  = cur * 24576;
        const int nxt = cur == 0 ? 2 : cur - 1;            // (kt+2)%3
        const bool st = (kt + 2) < NKT;
        s8v a4[4], b4[4];
        // ---- phase 0 (kk=0) ----
#pragma unroll
        for (int i = 0; i < 4; i++) {
            a4[i] = *(const s8v*)(lds + co + aoff + i * 1024 + colu0);
            b4[i] = *(const s8v*)(lds + co + boff + i * 1024 + colu0);
        }
        if (st) STG_H0(kt + 2, nxt);
        BAR(); SB0();
        __builtin_amdgcn_s_setprio(1);
#pragma unroll
        for (int mf = 0; mf < 4; mf++)
#pragma unroll
            for (int nf = 0; nf < 4; nf++)
                acc[mf][nf] = __builtin_amdgcn_mfma_f32_16x16x32_bf16(
                    a4[mf], b4[nf], acc[mf][nf], 0, 0, 0);
        __builtin_amdgcn_s_setprio(0);
        BAR(); SB0();
        // ---- phase 1 (kk=1) ----
#pragma unroll
        for (int i = 0; i < 4; i++) {
            a4[i] = *(const s8v*)(lds + co + aoff + i * 1024 + colu1);
            b4[i] = *(const s8v*)(lds + co + boff + i * 1024 + colu1);
        }
        if (st) STG_H1(kt + 2, nxt);
        BAR(); SB0();
        __builtin_amdgcn_s_setprio(1);
#pragma unroll
        for (int mf = 0; mf < 4; mf++)
#pragma unroll
            for (int nf = 0; nf < 4; nf++)
                acc[mf][nf] = __builtin_amdgcn_mfma_f32_16x16x32_bf16(
                    a4[mf], b4[nf], acc[mf][nf], 0, 0, 0);
        __builtin_amdgcn_s_setprio(0);
        SB0();
        if (kt + 1 < NKT) {                                 // gate next iter's ds_reads
            if (kt + 3 < NKT) asm volatile("s_waitcnt vmcnt(6)" ::: "memory");
            else              asm volatile("s_waitcnt vmcnt(0)" ::: "memory");
        }
        BAR(); SB0();
        cur = cur == 2 ? 0 : cur + 1;
    }
#undef STG_H0
#undef STG_H1
    // epilogue: C row = bm + wr*64 + mf*16 + (l>>4)*4 + i, col = bn + wc*64 + nf*16 + (l&15)
    const int r0 = bm + wr * 64 + ((l >> 4) << 2);
    const int c0 = bn + wc * 64 + (l & 15);
    const bool sig = (EPI == 0) && (bn >= sigoff);
#pragma unroll
    for (int mf = 0; mf < 4; mf++)
#pragma unroll
        for (int nf = 0; nf < 4; nf++)
#pragma unroll
            for (int i = 0; i < 4; i++) {
                size_t o = (size_t)(r0 + mf * 16 + i) * ldc + (c0 + nf * 16);
                float r = acc[mf][nf][i];
                if (EPI == 0) {
                    if (sig) r = 1.f / (1.f + __expf(-r));
                    ((u16*)outv)[o] = f2b(r);
                } else if (EPI == 2) {
                    float t = fmaxf(r, 0.f);
                    ((u16*)outv)[o] = f2b(t * t);
                } else if (EPI == 3) {
                    ((float*)outv)[o] = fmaf(b2f(e1[o]), r, e0[o]);
                } else if (EPI == 4) {
                    ((float*)outv)[o] = e0[o] + r;
                }
            }
}

// ---------------- WKV helpers ----------------
__device__ __forceinline__ void wkv_step(float& a, float& b, float& m,
                                         float w, float kt, float vt)
{
    float mm = fmaxf(m + w, kt);
    float e1 = __expf(m + w - mm);
    float e2 = __expf(kt - mm);
    a = e1 * a + e2 * vt;
    b = e1 * b + e2;
    m = mm;
}
__device__ __forceinline__ void wkv_merge(float& a, float& b, float& m,
                                          float shift, float a2, float b2, float m2)
{
    float ms = m + shift;
    float mm = fmaxf(ms, m2);
    float e1 = __expf(ms - mm);
    float e2 = __expf(m2 - mm);
    a = e1 * a + e2 * a2;
    b = e1 * b + e2 * b2;
    m = mm;
}

// ---------------- WKV pass 1: per-chunk fwd/bwd summaries ----------------
__global__ __launch_bounds__(256) void wkv_pass1(const u16* __restrict__ kvs,
    const float* __restrict__ decay, float* __restrict__ sums)
{
    int e = blockIdx.x * 256 + threadIdx.x;
    int idx = e % BC, ci = e / BC;
    int b = idx / Cv, c = idx % Cv;
    float w = decay[c] * (1.f / (float)Tv);
    size_t base = ((size_t)b * Tv + (size_t)ci * Lc) * KVS + c;
    const size_t P = (size_t)NCHK * BC;
    size_t so = (size_t)ci * BC + idx;
    float a = 0.f, bb = 0.f, m = -1e38f;
    for (int t = 0; t < Lc; t++) {
        size_t off = base + (size_t)t * KVS;
        wkv_step(a, bb, m, w, b2f(kvs[off]), b2f(kvs[off + 768]));
    }
    sums[0 * P + so] = a; sums[1 * P + so] = bb; sums[2 * P + so] = m;
    a = 0.f; bb = 0.f; m = -1e38f;
    for (int t = Lc - 1; t >= 0; t--) {
        size_t off = base + (size_t)t * KVS;
        wkv_step(a, bb, m, w, b2f(kvs[off]), b2f(kvs[off + 768]));
    }
    sums[3 * P + so] = a; sums[4 * P + so] = bb; sums[5 * P + so] = m;
}

// ---------------- WKV pass 2: scan chunk summaries -> exclusive checkpoints ----------------
__global__ __launch_bounds__(256) void wkv_pass2(const float* __restrict__ decay,
    const float* __restrict__ sums, float* __restrict__ chks)
{
    int idx = blockIdx.x * 256 + threadIdx.x;   // 0..BC-1
    int c = idx % Cv;
    float shift = decay[c] * (1.f / (float)Tv) * (float)Lc;
    const size_t P = (size_t)NCHK * BC;
    float a = 0.f, bb = 0.f, m = -1e38f;
    for (int ci = 0; ci < NCHK; ci++) {
        size_t so = (size_t)ci * BC + idx;
        chks[0 * P + so] = a; chks[1 * P + so] = bb; chks[2 * P + so] = m;
        wkv_merge(a, bb, m, shift, sums[0 * P + so], sums[1 * P + so], sums[2 * P + so]);
    }
    a = 0.f; bb = 0.f; m = -1e38f;
    for (int ci = NCHK - 1; ci >= 0; ci--) {
        size_t so = (size_t)ci * BC + idx;
        chks[3 * P + so] = a; chks[4 * P + so] = bb; chks[5 * P + so] = m;
        wkv_merge(a, bb, m, shift, sums[3 * P + so], sums[4 * P + so], sums[5 * P + so]);
    }
}

// ---------------- WKV pass 3: per-chunk combine, writes y*sr over k slot ----------------
__global__ __launch_bounds__(256) void wkv_pass3(u16* __restrict__ kvs,
    const float* __restrict__ decay, const float* __restrict__ first,
    const float* __restrict__ chks)
{
    int e = blockIdx.x * 256 + threadIdx.x;
    int idx = e % BC, ci = e / BC;
    int b = idx / Cv, c = idx % Cv;
    float w = decay[c] * (1.f / (float)Tv);
    float u = first[c] * (1.f / (float)Tv);
    const size_t P = (size_t)NCHK * BC;
    size_t so = (size_t)ci * BC + idx;
    size_t base = ((size_t)b * Tv + (size_t)ci * Lc) * KVS + c;
    float sa = chks[3 * P + so], sb2 = chks[4 * P + so], sm = chks[5 * P + so];
    float Ba[8], Bb[8], Bm[8];
#pragma unroll
    for (int si = 7; si >= 0; si--) {
        Ba[si] = sa; Bb[si] = sb2; Bm[si] = sm;
        for (int j = 15; j >= 0; j--) {
            size_t off = base + (size_t)(si * 16 + j) * KVS;
            wkv_step(sa, sb2, sm, w, b2f(kvs[off]), b2f(kvs[off + 768]));
        }
    }
    float fa = chks[0 * P + so], fb2 = chks[1 * P + so], fm = chks[2 * P + so];
#pragma unroll
    for (int si = 0; si < 8; si++) {
        float lk[16], lv[16], la[16], lb[16], lm[16];
        float ta = Ba[si], tb = Bb[si], tm = Bm[si];
#pragma unroll
        for (int j = 15; j >= 0; j--) {
            size_t off = base + (size_t)(si * 16 + j) * KVS;
            lk[j] = b2f(kvs[off]); lv[j] = b2f(kvs[off + 768]);
            la[j] = ta; lb[j] = tb; lm[j] = tm;
            wkv_step(ta, tb, tm, w, lk[j], lv[j]);
        }
#pragma unroll
        for (int j = 0; j < 16; j++) {
            float kk = lk[j] + u;
            float M  = fmaxf(fmaxf(fm, lm[j]), kk);
            float ef = __expf(fm - M);
            float eb = __expf(lm[j] - M);
            float ec = __expf(kk - M);
            float num = ef * fa + eb * la[j] + ec * lv[j];
            float den = ef * fb2 + eb * lb[j] + ec;
            size_t off = base + (size_t)(si * 16 + j) * KVS;
            kvs[off] = f2b(b2f(kvs[off + 1536]) * (num / den));  // y' = sr * y
            wkv_step(fa, fb2, fm, w, lk[j], lv[j]);
        }
    }
}

__global__ __launch_bounds__(256) void fill_signal(float* __restrict__ out, int n, float val)
{
    int i = blockIdx.x * 256 + threadIdx.x;
    if (i < n) out[i] = val;
}

extern "C" void kernel_launch(void* const* d_in, const int* in_sizes, int n_in,
                              void* d_out, int out_size, void* d_ws, size_t ws_size,
                              hipStream_t stream)
{
    const float* x     = (const float*)d_in[0];
    const float* ln1_w = (const float*)d_in[1];
    const float* ln1_b = (const float*)d_in[2];
    const float* ln2_w = (const float*)d_in[3];
    const float* ln2_b = (const float*)d_in[4];
    const float* decay = (const float*)d_in[5];
    const float* first = (const float*)d_in[6];
    const float* Wk_a  = (const float*)d_in[7];
    const float* Wv_a  = (const float*)d_in[8];
    const float* Wr_a  = (const float*)d_in[9];
    const float* Wo_a  = (const float*)d_in[10];
    const float* Wk_f  = (const float*)d_in[11];
    const float* Wv_f  = (const float*)d_in[12];
    const float* Wr_f  = (const float*)d_in[13];
    float* out = (float*)d_out;

    const size_t NCe = (size_t)BT * Cv;
    const size_t CC  = (size_t)Cv * Cv;
    const size_t HC  = (size_t)Hv * Cv;
    const size_t SUM = (size_t)6 * NCHK * BC;

    u16* hb    = (u16*)d_ws;                   // h / h2 (bf16)
    u16* kvs   = hb + NCe;                     // 3*NCe: k|v|sr interleaved (stride 2304)
    float* x1  = (float*)(kvs + 3 * NCe);      // fp32 x after attention
    u16* wKVR  = (u16*)(x1 + NCe);             // bf16 weights: [Wk;Wv;Wr] 2304x768
    u16* wOa   = wKVR + 3 * CC;
    u16* wRf   = wOa + CC;
    u16* wKf   = wRf + CC;
    u16* wVf   = wKf + HC;
    float* sums = (float*)(wVf + HC);
    float* chks = sums + SUM;
    u16* kfb_full = (u16*)(chks + SUM);
    size_t need_chunk = (size_t)((char*)kfb_full - (char*)d_ws);
    size_t need_full  = need_chunk + (size_t)BT * Hv * sizeof(u16);

    if (ws_size < need_chunk) {
        fill_signal<<<(int)((NCe + 255) / 256), 256, 0, stream>>>(out, (int)NCe, (float)(ws_size >> 20));
        return;
    }
    const bool full = (ws_size >= need_full);

    u16* gate = kvs;            // overlay: kvs dead after Wo-GEMM
    u16* kfb_c = kvs + NCe;     // 2*NCe = 8192*3072 (chunked FFN activation)

    dim3 blk(256);
    cvt_f2b<<<(int)(CC / 4 + 255) / 256, blk, 0, stream>>>(Wk_a, wKVR, (int)(CC / 4));
    cvt_f2b<<<(int)(CC / 4 + 255) / 256, blk, 0, stream>>>(Wv_a, wKVR + CC, (int)(CC / 4));
    cvt_f2b<<<(int)(CC / 4 + 255) / 256, blk, 0, stream>>>(Wr_a, wKVR + 2 * CC, (int)(CC / 4));
    cvt_f2b<<<(int)(CC / 4 + 255) / 256, blk, 0, stream>>>(Wo_a, wOa, (int)(CC / 4));
    cvt_f2b<<<(int)(CC / 4 + 255) / 256, blk, 0, stream>>>(Wr_f, wRf, (int)(CC / 4));
    cvt_f2b<<<(int)(HC / 4 + 255) / 256, blk, 0, stream>>>(Wk_f, wKf, (int)(HC / 4));
    cvt_f2b<<<(int)(HC / 4 + 255) / 256, blk, 0, stream>>>(Wv_f, wVf, (int)(HC / 4));

    const size_t SH = 3 * 24576 * sizeof(u16);   // 144 KiB dynamic LDS
    dim3 g512(512);

    // 1. h = LN1(x)
    ln_bf16<<<BT, blk, 0, stream>>>(x, ln1_w, ln1_b, hb);
    // 2. fused [k|v|sr] = h @ [Wk;Wv;Wr]^T  (sigmoid on cols >= 1536)
    gemm256<0><<<dim3(BT / 128, KVS / 256), g512, SH, stream>>>(
        hb, wKVR, kvs, Cv, Cv, Cv, KVS, 1536, nullptr, nullptr);
    // 3. bidirectional WKV (chunk-parallel); y*sr written over k slot
    wkv_pass1<<<(BC * NCHK) / 256, blk, 0, stream>>>(kvs, decay, sums);
    wkv_pass2<<<BC / 256, blk, 0, stream>>>(decay, sums, chks);
    wkv_pass3<<<(BC * NCHK) / 256, blk, 0, stream>>>(kvs, decay, first, chks);
    // 4. x1 = x + (sr*y) @ Wo^T
    gemm256<4><<<dim3(BT / 128, Cv / 256), g512, SH, stream>>>(
        kvs, wOa, x1, Cv, KVS, Cv, Cv, 0, x, nullptr);
    // 5. h2 = LN2(x1)
    ln_bf16<<<BT, blk, 0, stream>>>(x1, ln2_w, ln2_b, hb);
    // 6. gate = sigmoid(h2 @ Wr_f^T)  (kvs now dead -> overlay)
    gemm256<0><<<dim3(BT / 128, Cv / 256), g512, SH, stream>>>(
        hb, wRf, gate, Cv, Cv, Cv, Cv, -1, nullptr, nullptr);
    // 7. FFN
    if (full) {
        gemm256<2><<<dim3(BT / 128, Hv / 256), g512, SH, stream>>>(
            hb, wKf, kfb_full, Cv, Cv, Cv, Hv, 0, nullptr, nullptr);
        gemm256<3><<<dim3(BT / 128, Cv / 256), g512, SH, stream>>>(
            kfb_full, wVf, out, Hv, Hv, Hv, Cv, 0, x1, gate);
    } else {
        for (int j = 0; j < 2; j++) {
            size_t ro = (size_t)j * 8192;
            gemm256<2><<<dim3(8192 / 128, Hv / 256), g512, SH, stream>>>(
                hb + ro * Cv, wKf, kfb_c, Cv, Cv, Cv, Hv, 0, nullptr, nullptr);
            gemm256<3><<<dim3(8192 / 128, Cv / 256), g512, SH, stream>>>(
                kfb_c, wVf, out + ro * Cv, Hv, Hv, Hv, Cv, 0, x1 + ro * Cv, gate + ro * Cv);
        }
    }
}